// Round 8
// baseline (827.000 us; speedup 1.0000x reference)
//
#include <hip/hip_runtime.h>

#define N_NODES 50000
#define N_EDGES 100000
#define DD 32
#define STEPS 5

#define NPT 4            // nodes per thread (gru)
#define NPB 128          // nodes per block (gru)
#define CAT_STRIDE 100   // floats per cat row (96 + 4 pad)
#define SCAN_BLOCKS 196  // 196*256 = 50176 >= N_NODES

// prop[n,j] = emb[token[n],j]; also zero deg / cnt2 for the CSR build.
__global__ void init_prop(const int* __restrict__ token,
                          const float* __restrict__ emb,
                          float* __restrict__ prop,
                          unsigned* __restrict__ deg,
                          unsigned* __restrict__ cnt2) {
    int idx = blockIdx.x * 256 + threadIdx.x;   // over N*D = 1.6M, exact grid
    int n = idx >> 5, j = idx & 31;
    prop[idx] = emb[token[n] * DD + j];
    if (idx < N_NODES) deg[idx] = 0u;
    else if (idx < N_NODES + 2 * N_NODES) cnt2[idx - N_NODES] = 0u;
}

// Histogram: in-degree per dst node; packed-byte out-edge-type counts per src.
__global__ void build_hist(const int* __restrict__ etype,
                           const int* __restrict__ src,
                           const int* __restrict__ dst,
                           unsigned* __restrict__ deg,
                           unsigned* __restrict__ cnt2) {
    int e = blockIdx.x * 256 + threadIdx.x;
    if (e >= N_EDGES) return;
    atomicAdd(&deg[dst[e]], 1u);
    int t = etype[e], s = src[e];
    atomicAdd(&cnt2[s * 2 + (t >> 2)], 1u << (8 * (t & 3)));  // max count << 255
}

// Transpose W_edge[t,i,j,k] -> Wf[t,i,j] (k=0), Wrv[t,i,j] (k=1). 8192 exact.
__global__ void prep_W(const float* __restrict__ W_edge,
                       float* __restrict__ Wf, float* __restrict__ Wrv) {
    int idx = blockIdx.x * 256 + threadIdx.x;   // 32 * 256 = 8192 exact
    Wf[idx]  = W_edge[idx * 2];
    Wrv[idx] = W_edge[idx * 2 + 1];
}

// ---- parallel 3-phase scan (R7: single-block serial scan was 119 us) ----
__device__ __forceinline__ unsigned block_incl_scan(unsigned v, unsigned* lds) {
    int t = threadIdx.x;
    lds[t] = v;
    __syncthreads();
    for (int d = 1; d < 256; d <<= 1) {
        unsigned u = (t >= d) ? lds[t - d] : 0u;
        __syncthreads();
        lds[t] += u;
        __syncthreads();
    }
    return lds[t];
}

// Phase 1: per-block sum of deg
__global__ __launch_bounds__(256) void
scan_partials(const unsigned* __restrict__ deg, unsigned* __restrict__ partials) {
    __shared__ unsigned lds[256];
    int i = blockIdx.x * 256 + threadIdx.x;
    unsigned v = (i < N_NODES) ? deg[i] : 0u;
    unsigned incl = block_incl_scan(v, lds);
    if (threadIdx.x == 255) partials[blockIdx.x] = incl;
}

// Phase 2: one block scans the 196 partials into exclusive bases
__global__ __launch_bounds__(256) void
scan_bases(unsigned* __restrict__ partials, unsigned* __restrict__ bases) {
    __shared__ unsigned lds[256];
    int t = threadIdx.x;
    unsigned v = (t < SCAN_BLOCKS) ? partials[t] : 0u;
    unsigned incl = block_incl_scan(v, lds);
    if (t < SCAN_BLOCKS) bases[t] = incl - v;   // exclusive
}

// Phase 3: off[i] = base[b] + exclusive-in-block; also cursor and off[N]
__global__ __launch_bounds__(256) void
scan_fill(const unsigned* __restrict__ deg, const unsigned* __restrict__ bases,
          unsigned* __restrict__ off, unsigned* __restrict__ cursor) {
    __shared__ unsigned lds[256];
    int i = blockIdx.x * 256 + threadIdx.x;
    unsigned v = (i < N_NODES) ? deg[i] : 0u;
    unsigned incl = block_incl_scan(v, lds);
    unsigned o = bases[blockIdx.x] + incl - v;
    if (i < N_NODES) { off[i] = o; cursor[i] = o; }
    if (i == N_NODES - 1) off[N_NODES] = o + v;   // = N_EDGES
}

// Scatter edges into CSR-by-dst, packing (src<<3 | etype).
__global__ void scatter_edges(const int* __restrict__ etype,
                              const int* __restrict__ src,
                              const int* __restrict__ dst,
                              unsigned* __restrict__ cursor,
                              unsigned* __restrict__ eid) {
    int e = blockIdx.x * 256 + threadIdx.x;
    if (e >= N_EDGES) return;
    unsigned p = atomicAdd(&cursor[dst[e]], 1u);
    eid[p] = ((unsigned)src[e] << 3) | (unsigned)etype[e];
}

// Half-wave (32 lanes) per node, lane j = output column. No atomics.
// In-edges in masked chunks of 4 (4 gathers + 4 parallel fma chains in
// flight — R5 lesson: serial per-edge chains leave 10x on the table).
// Out side: compact present types, process 4-interleaved sharing shfl(p).
__global__ void message_kernel(const unsigned* __restrict__ off,
                               const unsigned* __restrict__ eid,
                               const unsigned* __restrict__ cnt2,
                               const float* __restrict__ Wf,
                               const float* __restrict__ Wrv,
                               const float* __restrict__ prop,
                               float* __restrict__ in_fea,
                               float* __restrict__ out_fea) {
    int n = blockIdx.x * 8 + (threadIdx.x >> 5);   // 6250 * 8 = 50000 exact
    int lane = threadIdx.x & 63;
    int j = threadIdx.x & 31;
    int base = lane & 32;
    float p = prop[n * DD + j];
    unsigned o0 = off[n], o1 = off[n + 1];

    float accI = 0.f;
    for (unsigned q = o0; q < o1; q += 4) {
        float h[4];
        const float* W[4];
#pragma unroll
        for (int k = 0; k < 4; ++k) {
            bool act = (q + k) < o1;               // uniform per half-wave
            unsigned v = act ? eid[q + k] : 0u;
            h[k] = act ? prop[(v >> 3) * DD + j] : 0.f;
            W[k] = Wf + (v & 7) * (DD * DD);
        }
        float a[4] = {0.f, 0.f, 0.f, 0.f};
#pragma unroll
        for (int i = 0; i < DD; ++i) {
#pragma unroll
            for (int k = 0; k < 4; ++k)
                a[k] = fmaf(__shfl(h[k], base + i), W[k][i * DD + j], a[k]);
        }
        accI += (a[0] + a[1]) + (a[2] + a[3]);
    }
    in_fea[n * DD + j] = accI;

    // compact present out-types (uniform per half-wave)
    unsigned c0 = cnt2[n * 2], c1 = cnt2[n * 2 + 1];
    int tl[8]; float cf[8]; int nt = 0;
#pragma unroll
    for (int t = 0; t < 8; ++t) {
        unsigned cnt = ((t < 4 ? c0 : c1) >> (8 * (t & 3))) & 0xFFu;
        if (cnt) { tl[nt] = t; cf[nt] = (float)cnt; ++nt; }
    }
    float accO = 0.f;
    for (int b = 0; b < nt; b += 4) {
        const float* W[4]; float cc[4];
#pragma unroll
        for (int k = 0; k < 4; ++k) {
            bool act = (b + k) < nt;
            W[k] = Wrv + (act ? tl[b + k] : 0) * (DD * DD);
            cc[k] = act ? cf[b + k] : 0.f;
        }
        float a[4] = {0.f, 0.f, 0.f, 0.f};
#pragma unroll
        for (int i = 0; i < DD; ++i) {
            float pi = __shfl(p, base + i);        // shared across 4 chains
#pragma unroll
            for (int k = 0; k < 4; ++k)
                a[k] = fmaf(pi, W[k][i * DD + j], a[k]);
        }
        accO += cc[0] * a[0] + cc[1] * a[1] + cc[2] * a[2] + cc[3] * a[3];
    }
    out_fea[n * DD + j] = accO;
}

__device__ __forceinline__ void fma4(float (&acc)[4], float c, const float4& w) {
    acc[0] = fmaf(c, w.x, acc[0]);
    acc[1] = fmaf(c, w.y, acc[1]);
    acc[2] = fmaf(c, w.z, acc[2]);
    acc[3] = fmaf(c, w.w, acc[3]);
}
__device__ __forceinline__ float sigm(float x) {
    return 1.f / (1.f + __expf(-x));
}
__device__ __forceinline__ float fast_tanh(float x) {
    x = fminf(fmaxf(x, -15.f), 15.f);
    float e = __expf(2.f * x);
    return (e - 1.f) / (e + 1.f);
}

// Block = 256 threads = 128 nodes; cat=[in|out|prop] staged to LDS.
__global__ __launch_bounds__(256) void
gru_kernel(const float* __restrict__ W_r, const float* __restrict__ b_r,
           const float* __restrict__ W_z, const float* __restrict__ b_z,
           const float* __restrict__ W_t, const float* __restrict__ b_t,
           const float* __restrict__ in_fea,
           const float* __restrict__ out_fea,
           float* __restrict__ prop,
           float* __restrict__ out2) {
    __shared__ float cat[NPB * CAT_STRIDE];           // 51.2 KB
    float4* cat4 = (float4*)cat;                      // row stride 25 float4
    const int tid = threadIdx.x;
    const int n0 = blockIdx.x * NPB;
    const int jq = tid & 7;
    const int ng = tid >> 3;

    {
        const float4* a4 = (const float4*)(in_fea  + (size_t)n0 * DD);
        const float4* b4 = (const float4*)(out_fea + (size_t)n0 * DD);
        const float4* p4 = (const float4*)(prop    + (size_t)n0 * DD);
        const float4 zz = {0.f, 0.f, 0.f, 0.f};
#pragma unroll
        for (int q = 0; q < 4; ++q) {
            int f = q * 256 + tid;
            int node = f >> 3;
            int c4 = f & 7;
            bool ok = (n0 + node) < N_NODES;
            cat4[node * 25 + c4]      = ok ? a4[f] : zz;
            cat4[node * 25 + 8 + c4]  = ok ? b4[f] : zz;
            cat4[node * 25 + 16 + c4] = ok ? p4[f] : zz;
        }
    }
    __syncthreads();

    // ---- phase A: r,z ----
    float r_[NPT][4], z_[NPT][4];
    {
        float4 br = ((const float4*)b_r)[jq];
        float4 bz = ((const float4*)b_z)[jq];
#pragma unroll
        for (int k = 0; k < NPT; ++k) {
            r_[k][0] = br.x; r_[k][1] = br.y; r_[k][2] = br.z; r_[k][3] = br.w;
            z_[k][0] = bz.x; z_[k][1] = bz.y; z_[k][2] = bz.z; z_[k][3] = bz.w;
        }
    }
#pragma unroll 1
    for (int g = 0; g < 24; ++g) {
        int m0 = g * 4;
        float4 wr[4], wz[4];
#pragma unroll
        for (int i = 0; i < 4; ++i) {
            wr[i] = ((const float4*)(W_r + (m0 + i) * DD))[jq];
            wz[i] = ((const float4*)(W_z + (m0 + i) * DD))[jq];
        }
#pragma unroll
        for (int k = 0; k < NPT; ++k) {
            float4 c = cat4[(ng + 32 * k) * 25 + g];
            fma4(r_[k], c.x, wr[0]); fma4(r_[k], c.y, wr[1]);
            fma4(r_[k], c.z, wr[2]); fma4(r_[k], c.w, wr[3]);
            fma4(z_[k], c.x, wz[0]); fma4(z_[k], c.y, wz[1]);
            fma4(z_[k], c.z, wz[2]); fma4(z_[k], c.w, wz[3]);
        }
    }

    float p_[NPT][4];
#pragma unroll
    for (int k = 0; k < NPT; ++k) {
        float4 p = cat4[(ng + 32 * k) * 25 + 16 + jq];
        p_[k][0] = p.x; p_[k][1] = p.y; p_[k][2] = p.z; p_[k][3] = p.w;
#pragma unroll
        for (int j = 0; j < 4; ++j) {
            r_[k][j] = sigm(r_[k][j]) * p_[k][j];     // r := r*p
            z_[k][j] = sigm(z_[k][j]);
        }
    }
    __syncthreads();
#pragma unroll
    for (int k = 0; k < NPT; ++k) {
        float4 rp = {r_[k][0], r_[k][1], r_[k][2], r_[k][3]};
        cat4[(ng + 32 * k) * 25 + 16 + jq] = rp;
    }
    __syncthreads();

    // ---- phase B: t ----
    float t_[NPT][4];
    {
        float4 bt = ((const float4*)b_t)[jq];
#pragma unroll
        for (int k = 0; k < NPT; ++k) {
            t_[k][0] = bt.x; t_[k][1] = bt.y; t_[k][2] = bt.z; t_[k][3] = bt.w;
        }
    }
#pragma unroll 1
    for (int g = 0; g < 24; ++g) {
        int m0 = g * 4;
        float4 wt[4];
#pragma unroll
        for (int i = 0; i < 4; ++i)
            wt[i] = ((const float4*)(W_t + (m0 + i) * DD))[jq];
#pragma unroll
        for (int k = 0; k < NPT; ++k) {
            float4 c = cat4[(ng + 32 * k) * 25 + g];
            fma4(t_[k], c.x, wt[0]); fma4(t_[k], c.y, wt[1]);
            fma4(t_[k], c.z, wt[2]); fma4(t_[k], c.w, wt[3]);
        }
    }

    // ---- update: prop = p + z*(tanh(t) - p); final step also writes out2 ----
#pragma unroll
    for (int k = 0; k < NPT; ++k) {
        int node = n0 + ng + 32 * k;
        if (node < N_NODES) {
            float4 o;
            o.x = fmaf(z_[k][0], fast_tanh(t_[k][0]) - p_[k][0], p_[k][0]);
            o.y = fmaf(z_[k][1], fast_tanh(t_[k][1]) - p_[k][1], p_[k][1]);
            o.z = fmaf(z_[k][2], fast_tanh(t_[k][2]) - p_[k][2], p_[k][2]);
            o.w = fmaf(z_[k][3], fast_tanh(t_[k][3]) - p_[k][3], p_[k][3]);
            ((float4*)(prop + (size_t)node * DD))[jq] = o;
            if (out2) ((float4*)(out2 + (size_t)node * DD))[jq] = o;
        }
    }
}

extern "C" void kernel_launch(void* const* d_in, const int* in_sizes, int n_in,
                              void* d_out, int out_size, void* d_ws, size_t ws_size,
                              hipStream_t stream) {
    const int*   token  = (const int*)d_in[0];
    const int*   etype  = (const int*)d_in[1];
    const int*   src    = (const int*)d_in[2];
    const int*   dst    = (const int*)d_in[3];
    const float* emb    = (const float*)d_in[4];
    const float* W_edge = (const float*)d_in[5];
    const float* W_r    = (const float*)d_in[6];
    const float* b_r    = (const float*)d_in[7];
    const float* W_z    = (const float*)d_in[8];
    const float* b_z    = (const float*)d_in[9];
    const float* W_t    = (const float*)d_in[10];
    const float* b_t    = (const float*)d_in[11];
    float* out = (float*)d_out;

    // workspace layout (4-byte units), ~20.7 MB total
    float*    prop     = (float*)d_ws;                   // 1,600,000 f
    float*    in_fea   = prop + 1600000;                 // 1,600,000 f
    float*    out_fea  = in_fea + 1600000;               // 1,600,000 f
    float*    Wf       = out_fea + 1600000;              // 8192 f
    float*    Wrv      = Wf + 8192;                      // 8192 f
    unsigned* off      = (unsigned*)(Wrv + 8192);        // 50,016 u32
    unsigned* cursor   = off + 50016;                    // 50,016 u32
    unsigned* deg      = cursor + 50016;                 // 50,016 u32
    unsigned* cnt2     = deg + 50016;                    // 100,000 u32
    unsigned* eid      = cnt2 + 100000;                  // 100,000 u32
    unsigned* partials = eid + 100000;                   // 256 u32
    unsigned* bases    = partials + 256;                 // 256 u32

    // ---- one-time build phase (amortized over 5 steps) ----
    init_prop<<<(N_NODES * DD) / 256, 256, 0, stream>>>(token, emb, prop, deg, cnt2);
    build_hist<<<(N_EDGES + 255) / 256, 256, 0, stream>>>(etype, src, dst, deg, cnt2);
    prep_W<<<32, 256, 0, stream>>>(W_edge, Wf, Wrv);     // 8192 pairs EXACT
    scan_partials<<<SCAN_BLOCKS, 256, 0, stream>>>(deg, partials);
    scan_bases<<<1, 256, 0, stream>>>(partials, bases);
    scan_fill<<<SCAN_BLOCKS, 256, 0, stream>>>(deg, bases, off, cursor);
    scatter_edges<<<(N_EDGES + 255) / 256, 256, 0, stream>>>(etype, src, dst,
                                                             cursor, eid);
    // ---- propagation ----
    for (int step = 0; step < STEPS; ++step) {
        message_kernel<<<N_NODES / 8, 256, 0, stream>>>(off, eid, cnt2, Wf, Wrv,
                                                        prop, in_fea, out_fea);
        gru_kernel<<<(N_NODES + NPB - 1) / NPB, 256, 0, stream>>>(
            W_r, b_r, W_z, b_z, W_t, b_t, in_fea, out_fea, prop,
            (step == STEPS - 1) ? out : nullptr);
    }
}

// Round 9
// 754.570 us; speedup vs baseline: 1.0960x; 1.0960x over previous
//
#include <hip/hip_runtime.h>

#define N_NODES 50000
#define N_EDGES 100000
#define DD 32
#define STEPS 5

#define NPT 4            // nodes per thread (gru)
#define NPB 128          // nodes per block (gru)
#define NSLOTS (2 * N_NODES)   // node-sides: [0,N)=in(by dst), [N,2N)=out(by src)
#define SCAN_BLOCKS 391        // ceil(100000/256)
#define EPW 32                 // edges per wave in edge_kernel

// prop[n,j] = emb[token[n],j]; zero deg2[2N] and binCount[8].
__global__ void init_prop(const int* __restrict__ token,
                          const float* __restrict__ emb,
                          float* __restrict__ prop,
                          unsigned* __restrict__ deg2,
                          unsigned* __restrict__ binCount) {
    int idx = blockIdx.x * 256 + threadIdx.x;   // 6250*256 = 1.6M exact
    int n = idx >> 5, j = idx & 31;
    prop[idx] = emb[token[n] * DD + j];
    if (idx < NSLOTS) deg2[idx] = 0u;
    else if (idx < NSLOTS + 8) binCount[idx - NSLOTS] = 0u;
}

// Per-side degrees + global type histogram (block-aggregated).
__global__ void hist_kernel(const int* __restrict__ etype,
                            const int* __restrict__ src,
                            const int* __restrict__ dst,
                            unsigned* __restrict__ deg2,
                            unsigned* __restrict__ binCount) {
    __shared__ unsigned hb[8];
    if (threadIdx.x < 8) hb[threadIdx.x] = 0u;
    __syncthreads();
    int e = blockIdx.x * 256 + threadIdx.x;
    if (e < N_EDGES) {
        atomicAdd(&deg2[dst[e]], 1u);
        atomicAdd(&deg2[N_NODES + src[e]], 1u);
        atomicAdd(&hb[etype[e]], 1u);
    }
    __syncthreads();
    if (threadIdx.x < 8) atomicAdd(&binCount[threadIdx.x], hb[threadIdx.x]);
}

// Exclusive scan of the 8 type bins (trivial).
__global__ void bin_scan(const unsigned* __restrict__ binCount,
                         unsigned* __restrict__ binCursor) {
    if (threadIdx.x == 0) {
        unsigned run = 0;
        for (int t = 0; t < 8; ++t) { binCursor[t] = run; run += binCount[t]; }
    }
}

// Counting-sort edges by type: srcT_sorted[p]=(src<<3|t), dst_sorted[p]=dst.
__global__ void sort_scatter(const int* __restrict__ etype,
                             const int* __restrict__ src,
                             const int* __restrict__ dst,
                             unsigned* __restrict__ binCursor,
                             unsigned* __restrict__ srcT_sorted,
                             unsigned* __restrict__ dst_sorted) {
    __shared__ unsigned hb[8], base[8];
    if (threadIdx.x < 8) hb[threadIdx.x] = 0u;
    __syncthreads();
    int e = blockIdx.x * 256 + threadIdx.x;
    unsigned rank = 0; int t = 0;
    if (e < N_EDGES) { t = etype[e]; rank = atomicAdd(&hb[t], 1u); }
    __syncthreads();
    if (threadIdx.x < 8)
        base[threadIdx.x] = hb[threadIdx.x]
            ? atomicAdd(&binCursor[threadIdx.x], hb[threadIdx.x]) : 0u;
    __syncthreads();
    if (e < N_EDGES) {
        unsigned pos = base[t] + rank;
        srcT_sorted[pos] = ((unsigned)src[e] << 3) | (unsigned)t;
        dst_sorted[pos]  = (unsigned)dst[e];
    }
}

// Wc[t][i][0..63] = [Wf row i (k=0) | Wrv row i (k=1)]
__global__ void prep_W(const float* __restrict__ W_edge, float* __restrict__ Wc) {
    int idx = blockIdx.x * 256 + threadIdx.x;   // 64*256 = 16384 exact
    int j = idx & 63, ti = idx >> 6;            // ti = t*32+i
    Wc[idx] = W_edge[(ti * 32 + (j & 31)) * 2 + (j >> 5)];
}

// ---- 3-phase scan over deg2[2N] -> off2 / cursor2 ----
__device__ __forceinline__ unsigned incl_scan_256(unsigned v, unsigned* lds) {
    int t = threadIdx.x;
    lds[t] = v; __syncthreads();
    for (int d = 1; d < 256; d <<= 1) {
        unsigned u = (t >= d) ? lds[t - d] : 0u;
        __syncthreads(); lds[t] += u; __syncthreads();
    }
    return lds[t];
}
__global__ __launch_bounds__(256) void
scan_partials(const unsigned* __restrict__ deg2, unsigned* __restrict__ partials) {
    __shared__ unsigned lds[256];
    int i = blockIdx.x * 256 + threadIdx.x;
    unsigned v = (i < NSLOTS) ? deg2[i] : 0u;
    unsigned incl = incl_scan_256(v, lds);
    if (threadIdx.x == 255) partials[blockIdx.x] = incl;
}
__global__ __launch_bounds__(512) void
scan_bases(const unsigned* __restrict__ partials, unsigned* __restrict__ bases) {
    __shared__ unsigned lds[512];
    int t = threadIdx.x;
    unsigned v = (t < SCAN_BLOCKS) ? partials[t] : 0u;
    lds[t] = v; __syncthreads();
    for (int d = 1; d < 512; d <<= 1) {
        unsigned u = (t >= d) ? lds[t - d] : 0u;
        __syncthreads(); lds[t] += u; __syncthreads();
    }
    if (t < SCAN_BLOCKS) bases[t] = lds[t] - v;   // exclusive
}
__global__ __launch_bounds__(256) void
scan_fill(const unsigned* __restrict__ deg2, const unsigned* __restrict__ bases,
          unsigned* __restrict__ off2, unsigned* __restrict__ cursor2) {
    __shared__ unsigned lds[256];
    int i = blockIdx.x * 256 + threadIdx.x;
    unsigned v = (i < NSLOTS) ? deg2[i] : 0u;
    unsigned incl = incl_scan_256(v, lds);
    unsigned o = bases[blockIdx.x] + incl - v;
    if (i < NSLOTS) { off2[i] = o; cursor2[i] = o; }
    if (i == NSLOTS - 1) off2[NSLOTS] = o + v;   // = 2E
}

// Fill CSR lists: lst entries are SORTED edge positions p.
__global__ void scatter_lists(const unsigned* __restrict__ srcT_sorted,
                              const unsigned* __restrict__ dst_sorted,
                              unsigned* __restrict__ cursor2,
                              unsigned* __restrict__ lst) {
    int p = blockIdx.x * 256 + threadIdx.x;
    if (p >= N_EDGES) return;
    unsigned d = dst_sorted[p];
    lst[atomicAdd(&cursor2[d], 1u)] = (unsigned)p;
    unsigned s = srcT_sorted[p] >> 3;
    lst[atomicAdd(&cursor2[N_NODES + s], 1u)] = (unsigned)p;
}

// One wave per 32 sorted edges. Lane j<32: fwd col j (Wf); lane>=32: rev col
// j-32 (Wrv). W held in 32 VGPRs/lane, reloaded only on type change (edges
// sorted by type -> <=1 change per chunk). h_src is wave-uniform -> s_load
// broadcast (no shfl/bpermute: R8's 2.47M LDS bank conflicts came from those).
// fea[p][0..63] written as one coalesced 256B store per edge.
__global__ __launch_bounds__(256) void
edge_kernel(const unsigned* __restrict__ srcT_sorted,
            const float* __restrict__ Wc,
            const float* __restrict__ prop,
            float* __restrict__ fea) {
    int wid = (blockIdx.x * 256 + threadIdx.x) >> 6;   // global wave id
    int lane = threadIdx.x & 63;
    if (wid >= N_EDGES / EPW) return;                  // 3125 waves
    int p0 = wid * EPW, p1 = p0 + EPW;
    float w[32];
    int tcur = -1;
    int e_nxt = __builtin_amdgcn_readfirstlane((int)srcT_sorted[p0]);
#pragma unroll 1
    for (int p = p0; p < p1; ++p) {
        int e = e_nxt;
        if (p + 1 < p1)
            e_nxt = __builtin_amdgcn_readfirstlane((int)srcT_sorted[p + 1]);
        int t = e & 7;
        if (t != tcur) {                               // scalar-uniform branch
            tcur = t;
#pragma unroll
            for (int i = 0; i < 32; ++i) w[i] = Wc[(t * 32 + i) * 64 + lane];
        }
        const float* hp = prop + (size_t)(e >> 3) * DD;  // uniform -> s_load
        float acc = 0.f;
#pragma unroll
        for (int i = 0; i < 32; ++i) acc = fmaf(hp[i], w[i], acc);
        fea[(size_t)p * 64 + lane] = acc;              // 256B coalesced
    }
}

__device__ __forceinline__ void fma4(float (&acc)[4], float c, const float4& w) {
    acc[0] = fmaf(c, w.x, acc[0]);
    acc[1] = fmaf(c, w.y, acc[1]);
    acc[2] = fmaf(c, w.z, acc[2]);
    acc[3] = fmaf(c, w.w, acc[3]);
}
__device__ __forceinline__ float sigm(float x) {
    return 1.f / (1.f + __expf(-x));
}
__device__ __forceinline__ float fast_tanh(float x) {
    x = fminf(fmaxf(x, -15.f), 15.f);
    float e = __expf(2.f * x);
    return (e - 1.f) / (e + 1.f);
}

// Block = 256 threads = 128 nodes. Staging now does the segment sums itself:
// cat[local][0..31] = sum of fea fwd rows over in-edges (CSR by dst),
// cat[local][32..63] = sum of fea rev rows over out-edges (CSR by src),
// cat[local][64..95] = prop. Then the two matvec phases as before.
__global__ __launch_bounds__(256) void
gru_kernel(const float* __restrict__ W_r, const float* __restrict__ b_r,
           const float* __restrict__ W_z, const float* __restrict__ b_z,
           const float* __restrict__ W_t, const float* __restrict__ b_t,
           const unsigned* __restrict__ off2,
           const unsigned* __restrict__ lst,
           const float* __restrict__ fea,
           float* __restrict__ prop,
           float* __restrict__ out2) {
    __shared__ float cat[NPB * 100];                  // 51.2 KB
    float4* cat4 = (float4*)cat;                      // row stride 25 float4
    const int tid = threadIdx.x;
    const int n0 = blockIdx.x * NPB;
    const int jq = tid & 7;
    const int ng = tid >> 3;

    // ---- staging: gather-sum fea rows per node-side ----
    {
        const int hw = tid >> 5, j = tid & 31;
#pragma unroll 1
        for (int k = 0; k < 16; ++k) {
            int local = hw + 8 * k;                   // 0..127
            int node = n0 + local;
            float accI = 0.f, accO = 0.f, pv = 0.f;
            if (node < N_NODES) {
                unsigned a0 = off2[node], a1 = off2[node + 1];
                for (unsigned q = a0; q < a1; ++q)
                    accI += fea[(size_t)lst[q] * 64 + j];
                unsigned b0 = off2[N_NODES + node], b1 = off2[N_NODES + node + 1];
                for (unsigned q = b0; q < b1; ++q)
                    accO += fea[(size_t)lst[q] * 64 + 32 + j];
                pv = prop[(size_t)node * DD + j];
            }
            cat[local * 100 + j]      = accI;
            cat[local * 100 + 32 + j] = accO;
            cat[local * 100 + 64 + j] = pv;
        }
    }
    __syncthreads();

    // ---- phase A: r,z ----
    float r_[NPT][4], z_[NPT][4];
    {
        float4 br = ((const float4*)b_r)[jq];
        float4 bz = ((const float4*)b_z)[jq];
#pragma unroll
        for (int k = 0; k < NPT; ++k) {
            r_[k][0] = br.x; r_[k][1] = br.y; r_[k][2] = br.z; r_[k][3] = br.w;
            z_[k][0] = bz.x; z_[k][1] = bz.y; z_[k][2] = bz.z; z_[k][3] = bz.w;
        }
    }
#pragma unroll 1
    for (int g = 0; g < 24; ++g) {
        int m0 = g * 4;
        float4 wr[4], wz[4];
#pragma unroll
        for (int i = 0; i < 4; ++i) {
            wr[i] = ((const float4*)(W_r + (m0 + i) * DD))[jq];
            wz[i] = ((const float4*)(W_z + (m0 + i) * DD))[jq];
        }
#pragma unroll
        for (int k = 0; k < NPT; ++k) {
            float4 c = cat4[(ng + 32 * k) * 25 + g];
            fma4(r_[k], c.x, wr[0]); fma4(r_[k], c.y, wr[1]);
            fma4(r_[k], c.z, wr[2]); fma4(r_[k], c.w, wr[3]);
            fma4(z_[k], c.x, wz[0]); fma4(z_[k], c.y, wz[1]);
            fma4(z_[k], c.z, wz[2]); fma4(z_[k], c.w, wz[3]);
        }
    }

    float p_[NPT][4];
#pragma unroll
    for (int k = 0; k < NPT; ++k) {
        float4 p = cat4[(ng + 32 * k) * 25 + 16 + jq];
        p_[k][0] = p.x; p_[k][1] = p.y; p_[k][2] = p.z; p_[k][3] = p.w;
#pragma unroll
        for (int j = 0; j < 4; ++j) {
            r_[k][j] = sigm(r_[k][j]) * p_[k][j];     // r := r*p
            z_[k][j] = sigm(z_[k][j]);
        }
    }
    __syncthreads();
#pragma unroll
    for (int k = 0; k < NPT; ++k) {
        float4 rp = {r_[k][0], r_[k][1], r_[k][2], r_[k][3]};
        cat4[(ng + 32 * k) * 25 + 16 + jq] = rp;
    }
    __syncthreads();

    // ---- phase B: t ----
    float t_[NPT][4];
    {
        float4 bt = ((const float4*)b_t)[jq];
#pragma unroll
        for (int k = 0; k < NPT; ++k) {
            t_[k][0] = bt.x; t_[k][1] = bt.y; t_[k][2] = bt.z; t_[k][3] = bt.w;
        }
    }
#pragma unroll 1
    for (int g = 0; g < 24; ++g) {
        int m0 = g * 4;
        float4 wt[4];
#pragma unroll
        for (int i = 0; i < 4; ++i)
            wt[i] = ((const float4*)(W_t + (m0 + i) * DD))[jq];
#pragma unroll
        for (int k = 0; k < NPT; ++k) {
            float4 c = cat4[(ng + 32 * k) * 25 + g];
            fma4(t_[k], c.x, wt[0]); fma4(t_[k], c.y, wt[1]);
            fma4(t_[k], c.z, wt[2]); fma4(t_[k], c.w, wt[3]);
        }
    }

    // ---- update: prop = p + z*(tanh(t) - p); final step also writes out2 ----
#pragma unroll
    for (int k = 0; k < NPT; ++k) {
        int node = n0 + ng + 32 * k;
        if (node < N_NODES) {
            float4 o;
            o.x = fmaf(z_[k][0], fast_tanh(t_[k][0]) - p_[k][0], p_[k][0]);
            o.y = fmaf(z_[k][1], fast_tanh(t_[k][1]) - p_[k][1], p_[k][1]);
            o.z = fmaf(z_[k][2], fast_tanh(t_[k][2]) - p_[k][2], p_[k][2]);
            o.w = fmaf(z_[k][3], fast_tanh(t_[k][3]) - p_[k][3], p_[k][3]);
            ((float4*)(prop + (size_t)node * DD))[jq] = o;
            if (out2) ((float4*)(out2 + (size_t)node * DD))[jq] = o;
        }
    }
}

extern "C" void kernel_launch(void* const* d_in, const int* in_sizes, int n_in,
                              void* d_out, int out_size, void* d_ws, size_t ws_size,
                              hipStream_t stream) {
    const int*   token  = (const int*)d_in[0];
    const int*   etype  = (const int*)d_in[1];
    const int*   src    = (const int*)d_in[2];
    const int*   dst    = (const int*)d_in[3];
    const float* emb    = (const float*)d_in[4];
    const float* W_edge = (const float*)d_in[5];
    const float* W_r    = (const float*)d_in[6];
    const float* b_r    = (const float*)d_in[7];
    const float* W_z    = (const float*)d_in[8];
    const float* b_z    = (const float*)d_in[9];
    const float* W_t    = (const float*)d_in[10];
    const float* b_t    = (const float*)d_in[11];
    float* out = (float*)d_out;

    // workspace layout (4-byte units), ~33.3 MiB total
    float*    prop      = (float*)d_ws;                  // 1,600,000
    float*    fea       = prop + 1600000;                // 6,400,000 (E*64)
    float*    Wc        = fea + 6400000;                 // 16,384
    unsigned* srcT      = (unsigned*)(Wc + 16384);       // 100,000
    unsigned* dstS      = srcT + 100000;                 // 100,000
    unsigned* deg2      = dstS + 100000;                 // 100,000
    unsigned* off2      = deg2 + 100000;                 // 100,001
    unsigned* cursor2   = off2 + 100001;                 // 100,000
    unsigned* lst       = cursor2 + 100000;              // 200,000
    unsigned* binCount  = lst + 200000;                  // 8
    unsigned* binCursor = binCount + 8;                  // 8
    unsigned* partials  = binCursor + 8;                 // 512
    unsigned* bases     = partials + 512;                // 512

    // ---- one-time build (amortized over 5 steps) ----
    init_prop<<<(N_NODES * DD) / 256, 256, 0, stream>>>(token, emb, prop,
                                                        deg2, binCount);
    hist_kernel<<<(N_EDGES + 255) / 256, 256, 0, stream>>>(etype, src, dst,
                                                           deg2, binCount);
    bin_scan<<<1, 64, 0, stream>>>(binCount, binCursor);
    sort_scatter<<<(N_EDGES + 255) / 256, 256, 0, stream>>>(etype, src, dst,
                                                            binCursor, srcT, dstS);
    prep_W<<<64, 256, 0, stream>>>(W_edge, Wc);          // 16384 exact
    scan_partials<<<SCAN_BLOCKS, 256, 0, stream>>>(deg2, partials);
    scan_bases<<<1, 512, 0, stream>>>(partials, bases);
    scan_fill<<<SCAN_BLOCKS, 256, 0, stream>>>(deg2, bases, off2, cursor2);
    scatter_lists<<<(N_EDGES + 255) / 256, 256, 0, stream>>>(srcT, dstS,
                                                             cursor2, lst);
    // ---- propagation ----
    for (int step = 0; step < STEPS; ++step) {
        edge_kernel<<<(N_EDGES / EPW) * 64 / 256 + 1, 256, 0, stream>>>(
            srcT, Wc, prop, fea);
        gru_kernel<<<(N_NODES + NPB - 1) / NPB, 256, 0, stream>>>(
            W_r, b_r, W_z, b_z, W_t, b_t, off2, lst, fea, prop,
            (step == STEPS - 1) ? out : nullptr);
    }
}

// Round 10
// 661.056 us; speedup vs baseline: 1.2510x; 1.1415x over previous
//
#include <hip/hip_runtime.h>

#define N_NODES 50000
#define N_EDGES 100000
#define DD 32
#define STEPS 5

#define NPT 4            // nodes per thread (gru)
#define NPB 128          // nodes per block (gru)
#define NSLOTS (2 * N_NODES)   // node-sides: [0,N)=in(by dst), [N,2N)=out(by src)
#define SCAN_BLOCKS 391        // ceil(100000/256)
#define EPW 32                 // edges per wave in edge_kernel

// prop[n,j] = emb[token[n],j]; zero deg2[2N] and binCount[8].
__global__ void init_prop(const int* __restrict__ token,
                          const float* __restrict__ emb,
                          float* __restrict__ prop,
                          unsigned* __restrict__ deg2,
                          unsigned* __restrict__ binCount) {
    int idx = blockIdx.x * 256 + threadIdx.x;   // 6250*256 = 1.6M exact
    int n = idx >> 5, j = idx & 31;
    prop[idx] = emb[token[n] * DD + j];
    if (idx < NSLOTS) deg2[idx] = 0u;
    else if (idx < NSLOTS + 8) binCount[idx - NSLOTS] = 0u;
}

// Per-side degrees + global type histogram (block-aggregated).
__global__ void hist_kernel(const int* __restrict__ etype,
                            const int* __restrict__ src,
                            const int* __restrict__ dst,
                            unsigned* __restrict__ deg2,
                            unsigned* __restrict__ binCount) {
    __shared__ unsigned hb[8];
    if (threadIdx.x < 8) hb[threadIdx.x] = 0u;
    __syncthreads();
    int e = blockIdx.x * 256 + threadIdx.x;
    if (e < N_EDGES) {
        atomicAdd(&deg2[dst[e]], 1u);
        atomicAdd(&deg2[N_NODES + src[e]], 1u);
        atomicAdd(&hb[etype[e]], 1u);
    }
    __syncthreads();
    if (threadIdx.x < 8) atomicAdd(&binCount[threadIdx.x], hb[threadIdx.x]);
}

// Exclusive scan of the 8 type bins (trivial).
__global__ void bin_scan(const unsigned* __restrict__ binCount,
                         unsigned* __restrict__ binCursor) {
    if (threadIdx.x == 0) {
        unsigned run = 0;
        for (int t = 0; t < 8; ++t) { binCursor[t] = run; run += binCount[t]; }
    }
}

// Counting-sort edges by type: srcT_sorted[p]=(src<<3|t), dst_sorted[p]=dst.
__global__ void sort_scatter(const int* __restrict__ etype,
                             const int* __restrict__ src,
                             const int* __restrict__ dst,
                             unsigned* __restrict__ binCursor,
                             unsigned* __restrict__ srcT_sorted,
                             unsigned* __restrict__ dst_sorted) {
    __shared__ unsigned hb[8], base[8];
    if (threadIdx.x < 8) hb[threadIdx.x] = 0u;
    __syncthreads();
    int e = blockIdx.x * 256 + threadIdx.x;
    unsigned rank = 0; int t = 0;
    if (e < N_EDGES) { t = etype[e]; rank = atomicAdd(&hb[t], 1u); }
    __syncthreads();
    if (threadIdx.x < 8)
        base[threadIdx.x] = hb[threadIdx.x]
            ? atomicAdd(&binCursor[threadIdx.x], hb[threadIdx.x]) : 0u;
    __syncthreads();
    if (e < N_EDGES) {
        unsigned pos = base[t] + rank;
        srcT_sorted[pos] = ((unsigned)src[e] << 3) | (unsigned)t;
        dst_sorted[pos]  = (unsigned)dst[e];
    }
}

// Wc[t][i][0..63] = [Wf row i (k=0) | Wrv row i (k=1)]
__global__ void prep_W(const float* __restrict__ W_edge, float* __restrict__ Wc) {
    int idx = blockIdx.x * 256 + threadIdx.x;   // 64*256 = 16384 exact
    int j = idx & 63, ti = idx >> 6;            // ti = t*32+i
    Wc[idx] = W_edge[(ti * 32 + (j & 31)) * 2 + (j >> 5)];
}

// ---- 3-phase scan over deg2[2N] -> off2 / cursor2 ----
__device__ __forceinline__ unsigned incl_scan_256(unsigned v, unsigned* lds) {
    int t = threadIdx.x;
    lds[t] = v; __syncthreads();
    for (int d = 1; d < 256; d <<= 1) {
        unsigned u = (t >= d) ? lds[t - d] : 0u;
        __syncthreads(); lds[t] += u; __syncthreads();
    }
    return lds[t];
}
__global__ __launch_bounds__(256) void
scan_partials(const unsigned* __restrict__ deg2, unsigned* __restrict__ partials) {
    __shared__ unsigned lds[256];
    int i = blockIdx.x * 256 + threadIdx.x;
    unsigned v = (i < NSLOTS) ? deg2[i] : 0u;
    unsigned incl = incl_scan_256(v, lds);
    if (threadIdx.x == 255) partials[blockIdx.x] = incl;
}
__global__ __launch_bounds__(512) void
scan_bases(const unsigned* __restrict__ partials, unsigned* __restrict__ bases) {
    __shared__ unsigned lds[512];
    int t = threadIdx.x;
    unsigned v = (t < SCAN_BLOCKS) ? partials[t] : 0u;
    lds[t] = v; __syncthreads();
    for (int d = 1; d < 512; d <<= 1) {
        unsigned u = (t >= d) ? lds[t - d] : 0u;
        __syncthreads(); lds[t] += u; __syncthreads();
    }
    if (t < SCAN_BLOCKS) bases[t] = lds[t] - v;   // exclusive
}
__global__ __launch_bounds__(256) void
scan_fill(const unsigned* __restrict__ deg2, const unsigned* __restrict__ bases,
          unsigned* __restrict__ off2, unsigned* __restrict__ cursor2) {
    __shared__ unsigned lds[256];
    int i = blockIdx.x * 256 + threadIdx.x;
    unsigned v = (i < NSLOTS) ? deg2[i] : 0u;
    unsigned incl = incl_scan_256(v, lds);
    unsigned o = bases[blockIdx.x] + incl - v;
    if (i < NSLOTS) { off2[i] = o; cursor2[i] = o; }
    if (i == NSLOTS - 1) off2[NSLOTS] = o + v;   // = 2E
}

// Fill CSR lists. Entry packs sorted edge position AND the target's local
// index within its gru block: (p << 7) | (target & 127). p < 100k -> 24+7
// bits, fits. Lets gru staging ds_add straight into the LDS cat tile.
__global__ void scatter_lists(const unsigned* __restrict__ srcT_sorted,
                              const unsigned* __restrict__ dst_sorted,
                              unsigned* __restrict__ cursor2,
                              unsigned* __restrict__ lst) {
    int p = blockIdx.x * 256 + threadIdx.x;
    if (p >= N_EDGES) return;
    unsigned d = dst_sorted[p];
    lst[atomicAdd(&cursor2[d], 1u)] = ((unsigned)p << 7) | (d & 127u);
    unsigned s = srcT_sorted[p] >> 3;
    lst[atomicAdd(&cursor2[N_NODES + s], 1u)] = ((unsigned)p << 7) | (s & 127u);
}

// One wave per 32 sorted edges. Lane j<32: fwd col j; lane>=32: rev col j-32.
// W in 32 VGPRs/lane, reloaded only on type change; h_src via s_load
// broadcast; one coalesced 256B store per edge. (R9 structure — unchanged.)
__global__ __launch_bounds__(256) void
edge_kernel(const unsigned* __restrict__ srcT_sorted,
            const float* __restrict__ Wc,
            const float* __restrict__ prop,
            float* __restrict__ fea) {
    int wid = (blockIdx.x * 256 + threadIdx.x) >> 6;   // global wave id
    int lane = threadIdx.x & 63;
    if (wid >= N_EDGES / EPW) return;                  // 3125 waves
    int p0 = wid * EPW, p1 = p0 + EPW;
    float w[32];
    int tcur = -1;
    int e_nxt = __builtin_amdgcn_readfirstlane((int)srcT_sorted[p0]);
#pragma unroll 1
    for (int p = p0; p < p1; ++p) {
        int e = e_nxt;
        if (p + 1 < p1)
            e_nxt = __builtin_amdgcn_readfirstlane((int)srcT_sorted[p + 1]);
        int t = e & 7;
        if (t != tcur) {                               // scalar-uniform branch
            tcur = t;
#pragma unroll
            for (int i = 0; i < 32; ++i) w[i] = Wc[(t * 32 + i) * 64 + lane];
        }
        const float* hp = prop + (size_t)(e >> 3) * DD;  // uniform -> s_load
        float acc = 0.f;
#pragma unroll
        for (int i = 0; i < 32; ++i) acc = fmaf(hp[i], w[i], acc);
        fea[(size_t)p * 64 + lane] = acc;              // 256B coalesced
    }
}

__device__ __forceinline__ void fma4(float (&acc)[4], float c, const float4& w) {
    acc[0] = fmaf(c, w.x, acc[0]);
    acc[1] = fmaf(c, w.y, acc[1]);
    acc[2] = fmaf(c, w.z, acc[2]);
    acc[3] = fmaf(c, w.w, acc[3]);
}
__device__ __forceinline__ float sigm(float x) {
    return 1.f / (1.f + __expf(-x));
}
__device__ __forceinline__ float fast_tanh(float x) {
    x = fminf(fmaxf(x, -15.f), 15.f);
    float e = __expf(2.f * x);
    return (e - 1.f) / (e + 1.f);
}

// Block = 256 threads = 128 nodes. R10 staging: EDGE-PARALLEL. The block's
// CSR segments are contiguous in lst; half-waves round-robin entries with
// x4 unroll (4 independent lst->fea gather chains in flight) and ds_add_f32
// into the LDS cat tile. (R9's node-serial staging was a 3-deep dependent
// chain at 1.5 waves/SIMD -> 89 us.)
__global__ __launch_bounds__(256) void
gru_kernel(const float* __restrict__ W_r, const float* __restrict__ b_r,
           const float* __restrict__ W_z, const float* __restrict__ b_z,
           const float* __restrict__ W_t, const float* __restrict__ b_t,
           const unsigned* __restrict__ off2,
           const unsigned* __restrict__ lst,
           const float* __restrict__ fea,
           float* __restrict__ prop,
           float* __restrict__ out2) {
    __shared__ float cat[NPB * 100];                  // 51.2 KB
    float4* cat4 = (float4*)cat;                      // row stride 25 float4
    const int tid = threadIdx.x;
    const int n0 = blockIdx.x * NPB;
    const int jq = tid & 7;
    const int ng = tid >> 3;
    const int nEnd = min(n0 + NPB, N_NODES);

    // ---- zero in/out columns, stage prop ----
    {
        const float4* p4 = (const float4*)(prop + (size_t)n0 * DD);
        const float4 zz = {0.f, 0.f, 0.f, 0.f};
#pragma unroll
        for (int q = 0; q < 4; ++q) {
            int f = q * 256 + tid;
            int node = f >> 3;
            int c4 = f & 7;
            bool ok = (n0 + node) < N_NODES;
            cat4[node * 25 + c4]      = zz;
            cat4[node * 25 + 8 + c4]  = zz;
            cat4[node * 25 + 16 + c4] = ok ? p4[f] : zz;
        }
    }
    __syncthreads();

    // ---- edge-parallel gather-accumulate into cat ----
    {
        const int hw = tid >> 5, j = tid & 31;
        // in-side: cols 0..31
        unsigned s0 = off2[n0], s1 = off2[nEnd];
        for (unsigned idx = s0 + hw * 4; idx < s1; idx += 32) {
            unsigned v[4]; float x[4];
#pragma unroll
            for (int k = 0; k < 4; ++k)
                v[k] = (idx + k < s1) ? lst[idx + k] : 0xFFFFFFFFu;
#pragma unroll
            for (int k = 0; k < 4; ++k)
                x[k] = (v[k] != 0xFFFFFFFFu)
                     ? fea[(size_t)(v[k] >> 7) * 64 + j] : 0.f;
#pragma unroll
            for (int k = 0; k < 4; ++k)
                if (v[k] != 0xFFFFFFFFu)
                    atomicAdd(&cat[(v[k] & 127u) * 100 + j], x[k]);
        }
        // out-side: cols 32..63
        unsigned t0 = off2[N_NODES + n0], t1 = off2[N_NODES + nEnd];
        for (unsigned idx = t0 + hw * 4; idx < t1; idx += 32) {
            unsigned v[4]; float x[4];
#pragma unroll
            for (int k = 0; k < 4; ++k)
                v[k] = (idx + k < t1) ? lst[idx + k] : 0xFFFFFFFFu;
#pragma unroll
            for (int k = 0; k < 4; ++k)
                x[k] = (v[k] != 0xFFFFFFFFu)
                     ? fea[(size_t)(v[k] >> 7) * 64 + 32 + j] : 0.f;
#pragma unroll
            for (int k = 0; k < 4; ++k)
                if (v[k] != 0xFFFFFFFFu)
                    atomicAdd(&cat[(v[k] & 127u) * 100 + 32 + j], x[k]);
        }
    }
    __syncthreads();

    // ---- phase A: r,z ----
    float r_[NPT][4], z_[NPT][4];
    {
        float4 br = ((const float4*)b_r)[jq];
        float4 bz = ((const float4*)b_z)[jq];
#pragma unroll
        for (int k = 0; k < NPT; ++k) {
            r_[k][0] = br.x; r_[k][1] = br.y; r_[k][2] = br.z; r_[k][3] = br.w;
            z_[k][0] = bz.x; z_[k][1] = bz.y; z_[k][2] = bz.z; z_[k][3] = bz.w;
        }
    }
#pragma unroll 1
    for (int g = 0; g < 24; ++g) {
        int m0 = g * 4;
        float4 wr[4], wz[4];
#pragma unroll
        for (int i = 0; i < 4; ++i) {
            wr[i] = ((const float4*)(W_r + (m0 + i) * DD))[jq];
            wz[i] = ((const float4*)(W_z + (m0 + i) * DD))[jq];
        }
#pragma unroll
        for (int k = 0; k < NPT; ++k) {
            float4 c = cat4[(ng + 32 * k) * 25 + g];
            fma4(r_[k], c.x, wr[0]); fma4(r_[k], c.y, wr[1]);
            fma4(r_[k], c.z, wr[2]); fma4(r_[k], c.w, wr[3]);
            fma4(z_[k], c.x, wz[0]); fma4(z_[k], c.y, wz[1]);
            fma4(z_[k], c.z, wz[2]); fma4(z_[k], c.w, wz[3]);
        }
    }

    float p_[NPT][4];
#pragma unroll
    for (int k = 0; k < NPT; ++k) {
        float4 p = cat4[(ng + 32 * k) * 25 + 16 + jq];
        p_[k][0] = p.x; p_[k][1] = p.y; p_[k][2] = p.z; p_[k][3] = p.w;
#pragma unroll
        for (int j = 0; j < 4; ++j) {
            r_[k][j] = sigm(r_[k][j]) * p_[k][j];     // r := r*p
            z_[k][j] = sigm(z_[k][j]);
        }
    }
    __syncthreads();
#pragma unroll
    for (int k = 0; k < NPT; ++k) {
        float4 rp = {r_[k][0], r_[k][1], r_[k][2], r_[k][3]};
        cat4[(ng + 32 * k) * 25 + 16 + jq] = rp;
    }
    __syncthreads();

    // ---- phase B: t ----
    float t_[NPT][4];
    {
        float4 bt = ((const float4*)b_t)[jq];
#pragma unroll
        for (int k = 0; k < NPT; ++k) {
            t_[k][0] = bt.x; t_[k][1] = bt.y; t_[k][2] = bt.z; t_[k][3] = bt.w;
        }
    }
#pragma unroll 1
    for (int g = 0; g < 24; ++g) {
        int m0 = g * 4;
        float4 wt[4];
#pragma unroll
        for (int i = 0; i < 4; ++i)
            wt[i] = ((const float4*)(W_t + (m0 + i) * DD))[jq];
#pragma unroll
        for (int k = 0; k < NPT; ++k) {
            float4 c = cat4[(ng + 32 * k) * 25 + g];
            fma4(t_[k], c.x, wt[0]); fma4(t_[k], c.y, wt[1]);
            fma4(t_[k], c.z, wt[2]); fma4(t_[k], c.w, wt[3]);
        }
    }

    // ---- update: prop = p + z*(tanh(t) - p); final step also writes out2 ----
#pragma unroll
    for (int k = 0; k < NPT; ++k) {
        int node = n0 + ng + 32 * k;
        if (node < N_NODES) {
            float4 o;
            o.x = fmaf(z_[k][0], fast_tanh(t_[k][0]) - p_[k][0], p_[k][0]);
            o.y = fmaf(z_[k][1], fast_tanh(t_[k][1]) - p_[k][1], p_[k][1]);
            o.z = fmaf(z_[k][2], fast_tanh(t_[k][2]) - p_[k][2], p_[k][2]);
            o.w = fmaf(z_[k][3], fast_tanh(t_[k][3]) - p_[k][3], p_[k][3]);
            ((float4*)(prop + (size_t)node * DD))[jq] = o;
            if (out2) ((float4*)(out2 + (size_t)node * DD))[jq] = o;
        }
    }
}

extern "C" void kernel_launch(void* const* d_in, const int* in_sizes, int n_in,
                              void* d_out, int out_size, void* d_ws, size_t ws_size,
                              hipStream_t stream) {
    const int*   token  = (const int*)d_in[0];
    const int*   etype  = (const int*)d_in[1];
    const int*   src    = (const int*)d_in[2];
    const int*   dst    = (const int*)d_in[3];
    const float* emb    = (const float*)d_in[4];
    const float* W_edge = (const float*)d_in[5];
    const float* W_r    = (const float*)d_in[6];
    const float* b_r    = (const float*)d_in[7];
    const float* W_z    = (const float*)d_in[8];
    const float* b_z    = (const float*)d_in[9];
    const float* W_t    = (const float*)d_in[10];
    const float* b_t    = (const float*)d_in[11];
    float* out = (float*)d_out;

    // workspace layout (4-byte units), ~33.3 MiB total
    float*    prop      = (float*)d_ws;                  // 1,600,000
    float*    fea       = prop + 1600000;                // 6,400,000 (E*64)
    float*    Wc        = fea + 6400000;                 // 16,384
    unsigned* srcT      = (unsigned*)(Wc + 16384);       // 100,000
    unsigned* dstS      = srcT + 100000;                 // 100,000
    unsigned* deg2      = dstS + 100000;                 // 100,000
    unsigned* off2      = deg2 + 100000;                 // 100,001
    unsigned* cursor2   = off2 + 100001;                 // 100,000
    unsigned* lst       = cursor2 + 100000;              // 200,000
    unsigned* binCount  = lst + 200000;                  // 8
    unsigned* binCursor = binCount + 8;                  // 8
    unsigned* partials  = binCursor + 8;                 // 512
    unsigned* bases     = partials + 512;                // 512

    // ---- one-time build (amortized over 5 steps) ----
    init_prop<<<(N_NODES * DD) / 256, 256, 0, stream>>>(token, emb, prop,
                                                        deg2, binCount);
    hist_kernel<<<(N_EDGES + 255) / 256, 256, 0, stream>>>(etype, src, dst,
                                                           deg2, binCount);
    bin_scan<<<1, 64, 0, stream>>>(binCount, binCursor);
    sort_scatter<<<(N_EDGES + 255) / 256, 256, 0, stream>>>(etype, src, dst,
                                                            binCursor, srcT, dstS);
    prep_W<<<64, 256, 0, stream>>>(W_edge, Wc);          // 16384 exact
    scan_partials<<<SCAN_BLOCKS, 256, 0, stream>>>(deg2, partials);
    scan_bases<<<1, 512, 0, stream>>>(partials, bases);
    scan_fill<<<SCAN_BLOCKS, 256, 0, stream>>>(deg2, bases, off2, cursor2);
    scatter_lists<<<(N_EDGES + 255) / 256, 256, 0, stream>>>(srcT, dstS,
                                                             cursor2, lst);
    // ---- propagation ----
    for (int step = 0; step < STEPS; ++step) {
        edge_kernel<<<(N_EDGES / EPW) * 64 / 256 + 1, 256, 0, stream>>>(
            srcT, Wc, prop, fea);
        gru_kernel<<<(N_NODES + NPB - 1) / NPB, 256, 0, stream>>>(
            W_r, b_r, W_z, b_z, W_t, b_t, off2, lst, fea, prop,
            (step == STEPS - 1) ? out : nullptr);
    }
}